// Round 6
// baseline (563.357 us; speedup 1.0000x reference)
//
#include <hip/hip_runtime.h>
#include <hip/hip_bf16.h>
#include <stdint.h>

#define HORIZON 12

typedef __bf16 bf16x8 __attribute__((ext_vector_type(8)));
typedef float  f32x16 __attribute__((ext_vector_type(16)));
typedef float  f32x4v __attribute__((ext_vector_type(4)));

__device__ __forceinline__ unsigned short f2bf(float f) {
  union { float f; uint32_t u; } v; v.f = f;
  return (unsigned short)((v.u + 0x7FFFu + ((v.u >> 16) & 1u)) >> 16);
}
__device__ __forceinline__ float bf2f(unsigned short s) {
  union { uint32_t u; float f; } v; v.u = ((uint32_t)s) << 16;
  return v.f;
}

__device__ __forceinline__ float sigm(float x) { return 1.0f / (1.0f + __expf(-x)); }
__device__ __forceinline__ float tanh_fast(float x) { return 1.0f - 2.0f / (__expf(2.0f * x) + 1.0f); }

#define MFMA(a, b, c) __builtin_amdgcn_mfma_f32_32x32x16_bf16(a, b, c, 0, 0, 0)

// ---------- prep: cast weights to bf16 in K-major slab layout + bias combos ----------
// Wb: matrix m in {Wih0,Whh0,Wih1,Whh1,Wlin} at m*196608 els; slab k (K16 window):
// el = m*196608 + (k*rows + r)*16 + kk  (r = output row, kk = k within window).
// Bc: [brz 2x256][bzz 2x256][bin 2x256][bhn 2x256][blin 256] f32.
__global__ void prep(const float* __restrict__ wih, const float* __restrict__ whh,
                     const float* __restrict__ wlin, const float* __restrict__ bih,
                     const float* __restrict__ bhh, const float* __restrict__ blin,
                     unsigned short* __restrict__ Wb, float* __restrict__ Bc) {
  const int stride = gridDim.x * blockDim.x;
  for (int i = blockIdx.x * blockDim.x + threadIdx.x; i < 215296; i += stride) {
    if (i < 212992) {
      const int e = i << 2;
      const float* src; int m, rel;
      if (e < 196608)      { src = wih + e;             m = 0; rel = e; }
      else if (e < 393216) { src = whh + (e - 196608);  m = 1; rel = e - 196608; }
      else if (e < 589824) { src = wih + (e - 196608);  m = 2; rel = e - 393216; }
      else if (e < 786432) { src = whh + (e - 393216);  m = 3; rel = e - 589824; }
      else                 { src = wlin + (e - 786432); m = 4; rel = e - 786432; }
      const int rows = (m < 4) ? 768 : 256;
      const int r = rel >> 8, c = rel & 255;
      const float4 v = *(const float4*)src;
      unsigned short* dst = Wb + m * 196608 + ((c >> 4) * rows + r) * 16 + (c & 15);
      dst[0] = f2bf(v.x); dst[1] = f2bf(v.y); dst[2] = f2bf(v.z); dst[3] = f2bf(v.w);
    } else {
      const int t = i - 212992;
      float v;
      if (t < 512)       { const int l = t >> 8,        d = t & 255; v = bih[l*768+d]     + bhh[l*768+d]; }
      else if (t < 1024) { const int l = (t-512) >> 8,  d = t & 255; v = bih[l*768+256+d] + bhh[l*768+256+d]; }
      else if (t < 1536) { const int l = (t-1024) >> 8, d = t & 255; v = bih[l*768+512+d]; }
      else if (t < 2048) { const int l = (t-1536) >> 8, d = t & 255; v = bhh[l*768+512+d]; }
      else               { v = blin[t - 2048]; }
      Bc[t] = v;
    }
  }
}

// ---------- persistent fused decoder ----------
// 256 blocks x 512 threads; block owns batch stripe [b0, b0+64).
// D[row=batch][col=dim]: A = x/h bf16 from LDS (batch rows), B = W^T fragments
// streamed from global INTO REGISTERS per wave (wave owns dims w*32..+31) ->
// no cross-wave dependency inside a pass -> no barriers inside passes.
// C/D: col = lane&31 = dim, row = (reg&3)+8*(reg>>2)+4*(lane>>5) = batch row.
// h state lives ONLY as bf16 in LDS (owner-exclusive RMW in epilogue).
// y output + one-time input reads are NON-TEMPORAL so the 201 MB y-stream
// does not evict the 1.7 MB L2-resident weight set (round-5 FETCH_SIZE showed
// weights re-fetched from HBM every t-step: 8 XCD x 1.7 MB x 12 = 163 MB).
// LDS x/h: [64 rows][256 dims] bf16, granule g at slot g^(row&31) (conflict-free).
__global__ __launch_bounds__(512) __attribute__((amdgpu_waves_per_eu(2, 2)))
void rnn_persist(
    const float* __restrict__ y0, const float* __restrict__ h0f,
    const unsigned short* __restrict__ Wb, const float* __restrict__ Bc,
    float* __restrict__ out) {
  extern __shared__ char lds[];
  char* XB = lds;            // 32 KB bf16 [64][256]
  char* H0 = lds + 32768;    // 32 KB
  char* H1 = lds + 65536;    // 32 KB
  char* SC = lds + 98304;    // 32 KB f32 [32][256] transpose scratch

  const int tid = threadIdx.x;
  const int w   = tid >> 6;
  const int l   = tid & 63;
  const int l31 = l & 31;
  const int hi  = l >> 5;
  const int b0  = blockIdx.x * 64;
  const int dw  = w * 32 + l31;          // this lane's output dim
  const int sub2 = (l31 & 7) * 2;        // byte pos of dim within its granule
  const int gdw  = w * 4 + (l31 >> 3);   // dim-granule index of dw

  f32x16 Ar[2], Az[2], Ai[2], Ah[2];

  // ---- init XB = bf16(y0 stripe), swizzled (nt loads: one-time stream) ----
#pragma unroll
  for (int rr = 0; rr < 8; ++rr) {
    const int idx = rr * 2048 + tid * 4;
    const int row = idx >> 8, dd = idx & 255;
    const f32x4v v = __builtin_nontemporal_load(
        (const f32x4v*)(y0 + (size_t)(b0 + row) * 256 + dd));
    ushort4 o; o.x = f2bf(v.x); o.y = f2bf(v.y); o.z = f2bf(v.z); o.w = f2bf(v.w);
    *(ushort4*)(XB + row * 512 + (((dd >> 3) ^ (row & 31)) << 4) + (dd & 7) * 2) = o;
  }

  // ---- init H0/H1 = bf16(h0 stripes), swizzled ----
  auto initH = [&](const float* src, char* Hl) {
#pragma unroll
    for (int rr = 0; rr < 8; ++rr) {
      const int idx = rr * 2048 + tid * 4;
      const int row = idx >> 8, dd = idx & 255;
      const f32x4v v = __builtin_nontemporal_load(
          (const f32x4v*)(src + (size_t)(b0 + row) * 256 + dd));
      ushort4 o; o.x = f2bf(v.x); o.y = f2bf(v.y); o.z = f2bf(v.z); o.w = f2bf(v.w);
      *(ushort4*)(Hl + row * 512 + (((dd >> 3) ^ (row & 31)) << 4) + (dd & 7) * 2) = o;
    }
  };
  initH(h0f, H0);
  initH(h0f + (size_t)16384 * 256, H1);
  __syncthreads();

  const char* Wp = (const char*)Wb;

  auto zacc = [&](f32x16 (&A)[2]) {
#pragma unroll
    for (int ct = 0; ct < 2; ++ct)
#pragma unroll
      for (int r = 0; r < 16; ++r) A[ct][r] = 0.0f;
  };

  // fused gi+gh pass: 16 K16 iters, 6 reg-streamed W frags, 12 MFMA/iter
  auto passGRU = [&](const char* Xs, const char* Hs, size_t mI, size_t mH) {
    const char* bI0 = Wp + mI + (size_t)(0 * 256 + dw) * 32 + hi * 16;
    const char* bI1 = Wp + mI + (size_t)(1 * 256 + dw) * 32 + hi * 16;
    const char* bI2 = Wp + mI + (size_t)(2 * 256 + dw) * 32 + hi * 16;
    const char* bH0 = Wp + mH + (size_t)(0 * 256 + dw) * 32 + hi * 16;
    const char* bH1 = Wp + mH + (size_t)(1 * 256 + dw) * 32 + hi * 16;
    const char* bH2 = Wp + mH + (size_t)(2 * 256 + dw) * 32 + hi * 16;
    bf16x8 c0 = *(const bf16x8*)bI0, c1 = *(const bf16x8*)bI1, c2 = *(const bf16x8*)bI2;
    bf16x8 c3 = *(const bf16x8*)bH0, c4 = *(const bf16x8*)bH1, c5 = *(const bf16x8*)bH2;
#pragma unroll 4
    for (int k = 0; k < 16; ++k) {
      const int o = (k < 15) ? (k + 1) * 24576 : 0;   // slab stride = 768*32 B
      const bf16x8 n0 = *(const bf16x8*)(bI0 + o);
      const bf16x8 n1 = *(const bf16x8*)(bI1 + o);
      const bf16x8 n2 = *(const bf16x8*)(bI2 + o);
      const bf16x8 n3 = *(const bf16x8*)(bH0 + o);
      const bf16x8 n4 = *(const bf16x8*)(bH1 + o);
      const bf16x8 n5 = *(const bf16x8*)(bH2 + o);
      const int go = ((2 * k + hi) ^ l31) << 4;
      bf16x8 aX[2], aH[2];
#pragma unroll
      for (int ct = 0; ct < 2; ++ct) {
        aX[ct] = *(const bf16x8*)(Xs + (ct * 32 + l31) * 512 + go);
        aH[ct] = *(const bf16x8*)(Hs + (ct * 32 + l31) * 512 + go);
      }
#pragma unroll
      for (int ct = 0; ct < 2; ++ct) {
        Ar[ct] = MFMA(aX[ct], c0, Ar[ct]);
        Az[ct] = MFMA(aX[ct], c1, Az[ct]);
        Ai[ct] = MFMA(aX[ct], c2, Ai[ct]);
        Ar[ct] = MFMA(aH[ct], c3, Ar[ct]);
        Az[ct] = MFMA(aH[ct], c4, Az[ct]);
        Ah[ct] = MFMA(aH[ct], c5, Ah[ct]);
      }
      c0 = n0; c1 = n1; c2 = n2; c3 = n3; c4 = n4; c5 = n5;
    }
  };

  auto passLin = [&](const char* Hs, size_t mL) {
    const char* bL = Wp + mL + (size_t)dw * 32 + hi * 16;
    bf16x8 c = *(const bf16x8*)bL;
#pragma unroll 4
    for (int k = 0; k < 16; ++k) {
      const int o = (k < 15) ? (k + 1) * 8192 : 0;    // slab stride = 256*32 B
      const bf16x8 n = *(const bf16x8*)(bL + o);
      const int go = ((2 * k + hi) ^ l31) << 4;
      const bf16x8 a0 = *(const bf16x8*)(Hs + l31 * 512 + go);
      const bf16x8 a1 = *(const bf16x8*)(Hs + (32 + l31) * 512 + go);
      Ar[0] = MFMA(a0, c, Ar[0]);
      Ar[1] = MFMA(a1, c, Ar[1]);
      c = n;
    }
  };

  // GRU epilogue: owner-exclusive bf16 RMW of h in LDS, gates in fp32
  auto epi = [&](int L, char* Hl) {
    const float brz = Bc[L * 256 + dw];
    const float bzz = Bc[512 + L * 256 + dw];
    const float bin = Bc[1024 + L * 256 + dw];
    const float bhn = Bc[1536 + L * 256 + dw];
#pragma unroll
    for (int ct = 0; ct < 2; ++ct) {
#pragma unroll
      for (int reg = 0; reg < 16; ++reg) {
        const int rl = (reg & 3) + 8 * (reg >> 2) + 4 * hi;
        unsigned short* hp =
            (unsigned short*)(Hl + (ct * 32 + rl) * 512 + ((gdw ^ rl) << 4) + sub2);
        const float hold = bf2f(*hp);
        const float rg = sigm(Ar[ct][reg] + brz);
        const float zg = sigm(Az[ct][reg] + bzz);
        const float nn = tanh_fast(Ai[ct][reg] + bin + rg * (Ah[ct][reg] + bhn));
        const float hv = (1.0f - zg) * nn + zg * hold;
        *hp = f2bf(hv);
      }
    }
  };

#pragma unroll 1
  for (int t = 0; t < HORIZON; ++t) {
    // layer 0: gi(XB) + gh(H0-old) fused
    zacc(Ar); zacc(Az); zacc(Ai); zacc(Ah);
    passGRU(XB, H0, 0, 393216);
    __syncthreads();            // all pass reads of H0-old done
    epi(0, H0);
    __syncthreads();            // H0-new visible
    // layer 1: gi(H0-new) + gh(H1-old)
    zacc(Ar); zacc(Az); zacc(Ai); zacc(Ah);
    passGRU(H0, H1, 786432, 1179648);
    __syncthreads();
    epi(1, H1);
    __syncthreads();
    // output linear
    zacc(Ar);
    passLin(H1, 1572864);
    const float bl = Bc[2048 + dw];
#pragma unroll
    for (int ct = 0; ct < 2; ++ct) {
      // scatter fp32 y (reg layout) -> SC
#pragma unroll
      for (int reg = 0; reg < 16; ++reg) {
        const int rl = (reg & 3) + 8 * (reg >> 2) + 4 * hi;
        *(float*)(SC + rl * 1024 + dw * 4) = Ar[ct][reg] + bl;
      }
      __syncthreads();
      // cooperative coalesced NT store + bf16 next-x write
      float* og = out + ((size_t)t * 16384 + b0 + ct * 32) * 256;
#pragma unroll
      for (int rr = 0; rr < 4; ++rr) {
        const int idx = rr * 2048 + tid * 4;
        const int row = idx >> 8, dd = idx & 255;
        const f32x4v v = *(const f32x4v*)(SC + row * 1024 + dd * 4);
        __builtin_nontemporal_store(v, (f32x4v*)(og + row * 256 + dd));
        ushort4 o; o.x = f2bf(v.x); o.y = f2bf(v.y); o.z = f2bf(v.z); o.w = f2bf(v.w);
        const int xr = ct * 32 + row;
        *(ushort4*)(XB + xr * 512 + (((dd >> 3) ^ (xr & 31)) << 4) + (dd & 7) * 2) = o;
      }
      __syncthreads();
    }
  }
}

// ---------- launch ----------
extern "C" void kernel_launch(void* const* d_in, const int* in_sizes, int n_in,
                              void* d_out, int out_size, void* d_ws, size_t ws_size,
                              hipStream_t stream) {
  (void)in_sizes; (void)n_in; (void)out_size; (void)ws_size;
  const float* y0   = (const float*)d_in[0];
  const float* h0   = (const float*)d_in[1];
  const float* wih  = (const float*)d_in[2];
  const float* whh  = (const float*)d_in[3];
  const float* bih  = (const float*)d_in[4];
  const float* bhh  = (const float*)d_in[5];
  const float* wlin = (const float*)d_in[6];
  const float* blin = (const float*)d_in[7];
  float* out = (float*)d_out;

  unsigned short* Wb = (unsigned short*)d_ws;            // 851968 bf16 els
  float* Bc = (float*)((char*)d_ws + 1703936);           // 2304 f32

  static bool attr_done = false;
  if (!attr_done) {
    hipFuncSetAttribute((const void*)rnn_persist,
                        hipFuncAttributeMaxDynamicSharedMemorySize, 131072);
    attr_done = true;
  }

  prep<<<512, 256, 0, stream>>>(wih, whh, wlin, bih, bhh, blin, Wb, Bc);
  rnn_persist<<<256, 512, 131072, stream>>>(y0, h0, Wb, Bc, out);
}